// Round 1
// baseline (740.142 us; speedup 1.0000x reference)
//
#include <hip/hip_runtime.h>
#include <math.h>

#define HH 160
#define WW 160
#define DD 160
#define VOL (HH*WW*DD)          // 4,096,000
#define KS 11
#define PAD 5
#define NBATCH 2
#define NTOT (NBATCH*VOL)

struct Wts { float w[KS]; };

__device__ __forceinline__ int mirror(int i, int n) {
    if (i < 0) i = -i;
    if (i >= n) i = 2*n - 2 - i;
    return i;
}

__global__ void init_out(float* out) {
    if (threadIdx.x == 0 && blockIdx.x == 0) out[0] = 1.0f;
}

// Pass 1: blur along D (contiguous), compute 5 product channels on the fly.
__global__ void pass1(const float* __restrict__ src, const float* __restrict__ ref,
                      float* __restrict__ A, Wts wts) {
    int i = blockIdx.x * blockDim.x + threadIdx.x;
    if (i >= VOL) return;
    int d  = i % DD;
    int hw = i / DD;
    const float* sp = src + (long)hw * DD;
    const float* rp = ref + (long)hw * DD;
    float a0=0.f, a1=0.f, a2=0.f, a3=0.f, a4=0.f;
#pragma unroll
    for (int t = 0; t < KS; ++t) {
        int z = mirror(d + t - PAD, DD);
        float wt = wts.w[t];
        float s = sp[z], r = rp[z];
        a0 += wt*s; a1 += wt*r; a2 += wt*s*s; a3 += wt*r*r; a4 += wt*s*r;
    }
    A[0L*VOL + i] = a0;
    A[1L*VOL + i] = a1;
    A[2L*VOL + i] = a2;
    A[3L*VOL + i] = a3;
    A[4L*VOL + i] = a4;
}

// Pass 2: blur along W (stride DD floats) for all 5 channels.
__global__ void pass2(const float* __restrict__ A, float* __restrict__ Bf, Wts wts) {
    long i = (long)blockIdx.x * blockDim.x + threadIdx.x;
    if (i >= 5L*VOL) return;
    int v = (int)(i % VOL);
    int c = (int)(i / VOL);
    int d = v % DD;
    int w = (v / DD) % WW;
    int h = v / (DD*WW);
    const float* base = A + (long)c*VOL + (long)h*WW*DD + d;
    float acc = 0.f;
#pragma unroll
    for (int t = 0; t < KS; ++t) {
        int wm = mirror(w + t - PAD, WW);
        acc += wts.w[t] * base[(long)wm * DD];
    }
    Bf[i] = acc;
}

// Pass 3: blur along H (stride WW*DD floats), SSIM formula, reduce.
__global__ void pass3(const float* __restrict__ Bf, float* __restrict__ out,
                      Wts wts, float scale) {
    int v = blockIdx.x * blockDim.x + threadIdx.x;
    float ssim = 0.f;
    if (v < VOL) {
        int d = v % DD;
        int w = (v / DD) % WW;
        int h = v / (DD*WW);
        float mv[5];
#pragma unroll
        for (int c = 0; c < 5; ++c) {
            const float* base = Bf + (long)c*VOL + (long)w*DD + d;
            float a = 0.f;
#pragma unroll
            for (int t = 0; t < KS; ++t) {
                int hm = mirror(h + t - PAD, HH);
                a += wts.w[t] * base[(long)hm * WW * DD];
            }
            mv[c] = a;
        }
        float mu1 = mv[0], mu2 = mv[1], m11 = mv[2], m22 = mv[3], m12 = mv[4];
        float mu1sq = mu1*mu1, mu2sq = mu2*mu2, mu12 = mu1*mu2;
        float s1 = m11 - mu1sq, s2 = m22 - mu2sq, s12 = m12 - mu12;
        const float C1 = 1e-4f, C2 = 9e-4f;
        float num = (2.f*mu12 + C1) * (2.f*s12 + C2);
        float den = (mu1sq + mu2sq + C1) * (s1 + s2 + C2);
        ssim = num / (den + 1e-12f);
    }
    // 64-lane wave reduce
#pragma unroll
    for (int off = 32; off > 0; off >>= 1)
        ssim += __shfl_down(ssim, off, 64);
    __shared__ float lsum[4];
    int lane = threadIdx.x & 63, wid = threadIdx.x >> 6;
    if (lane == 0) lsum[wid] = ssim;
    __syncthreads();
    if (threadIdx.x == 0) {
        float s = lsum[0] + lsum[1] + lsum[2] + lsum[3];
        atomicAdd(out, -s * scale);
    }
}

// Fallback: brute-force 11^3 taps per voxel (used only if ws too small).
__global__ void brute(const float* __restrict__ src, const float* __restrict__ ref,
                      float* __restrict__ out, Wts wts, float scale) {
    long gi = (long)blockIdx.x * blockDim.x + threadIdx.x;
    float ssim = 0.f;
    if (gi < NTOT) {
        int v = (int)(gi % VOL);
        int b = (int)(gi / VOL);
        int d = v % DD;
        int w = (v / DD) % WW;
        int h = v / (DD*WW);
        const float* sp = src + (long)b * VOL;
        const float* rp = ref + (long)b * VOL;
        float a0=0.f,a1=0.f,a2=0.f,a3=0.f,a4=0.f;
        for (int i = 0; i < KS; ++i) {
            int hm = mirror(h + i - PAD, HH);
            float wx = wts.w[i];
            for (int j = 0; j < KS; ++j) {
                int wm = mirror(w + j - PAD, WW);
                float wxy = wx * wts.w[j];
                const float* sr = sp + ((long)hm*WW + wm) * DD;
                const float* rr = rp + ((long)hm*WW + wm) * DD;
                for (int k = 0; k < KS; ++k) {
                    int dm = mirror(d + k - PAD, DD);
                    float wt = wxy * wts.w[k];
                    float s = sr[dm], r = rr[dm];
                    a0 += wt*s; a1 += wt*r; a2 += wt*s*s; a3 += wt*r*r; a4 += wt*s*r;
                }
            }
        }
        float mu1sq = a0*a0, mu2sq = a1*a1, mu12 = a0*a1;
        float s1 = a2 - mu1sq, s2 = a3 - mu2sq, s12 = a4 - mu12;
        const float C1 = 1e-4f, C2 = 9e-4f;
        float num = (2.f*mu12 + C1) * (2.f*s12 + C2);
        float den = (mu1sq + mu2sq + C1) * (s1 + s2 + C2);
        ssim = num / (den + 1e-12f);
    }
#pragma unroll
    for (int off = 32; off > 0; off >>= 1)
        ssim += __shfl_down(ssim, off, 64);
    __shared__ float lsum[4];
    int lane = threadIdx.x & 63, wid = threadIdx.x >> 6;
    if (lane == 0) lsum[wid] = ssim;
    __syncthreads();
    if (threadIdx.x == 0) {
        float s = lsum[0] + lsum[1] + lsum[2] + lsum[3];
        atomicAdd(out, -s * scale);
    }
}

extern "C" void kernel_launch(void* const* d_in, const int* in_sizes, int n_in,
                              void* d_out, int out_size, void* d_ws, size_t ws_size,
                              hipStream_t stream) {
    const float* src = (const float*)d_in[0];
    const float* ref = (const float*)d_in[1];
    float* out = (float*)d_out;

    // Host-computed normalized 1D Gaussian (double precision, matches jnp).
    Wts wts;
    {
        double g[KS], s = 0.0;
        for (int i = 0; i < KS; ++i) {
            double a = (double)i - (KS - 1) / 2.0;
            g[i] = exp(-(a*a) / (2.0 * 1.5 * 1.5));
            s += g[i];
        }
        for (int i = 0; i < KS; ++i) wts.w[i] = (float)(g[i] / s);
    }

    const float scale = 1.0f / (float)NTOT;
    const size_t bufBytes = (size_t)5 * VOL * sizeof(float);   // 81,920,000
    const size_t need = 2 * bufBytes;                          // 163,840,000

    init_out<<<1, 64, 0, stream>>>(out);

    if (ws_size >= need) {
        float* A  = (float*)d_ws;
        float* Bf = (float*)((char*)d_ws + bufBytes);
        const int BLK = 256;
        const int g1 = (VOL + BLK - 1) / BLK;          // 16000
        const int g2 = (5*VOL + BLK - 1) / BLK;        // 80000
        for (int b = 0; b < NBATCH; ++b) {
            pass1<<<g1, BLK, 0, stream>>>(src + (long)b*VOL, ref + (long)b*VOL, A, wts);
            pass2<<<g2, BLK, 0, stream>>>(A, Bf, wts);
            pass3<<<g1, BLK, 0, stream>>>(Bf, out, wts, scale);
        }
    } else {
        const int BLK = 256;
        const long g = (NTOT + BLK - 1) / BLK;
        brute<<<(int)g, BLK, 0, stream>>>(src, ref, out, wts, scale);
    }
}

// Round 2
// 274.826 us; speedup vs baseline: 2.6931x; 2.6931x over previous
//
#include <hip/hip_runtime.h>
#include <math.h>

#define HH 160
#define WW 160
#define DD 160
#define VOL (HH*WW*DD)          // 4,096,000
#define KS 11
#define PAD 5
#define NBATCH 2
#define NTOT (NBATCH*VOL)
#define TH 16                    // h-outputs per thread in pass3 (10 chunks)
#define TW 16                    // w-outputs per thread in pass2 (10 chunks)

struct Wts { float w[KS]; };

__device__ __forceinline__ int mirror(int i, int n) {
    if (i < 0) i = -i;
    if (i >= n) i = 2*n - 2 - i;
    return i;
}

__global__ void init_out(float* out) {
    if (threadIdx.x == 0 && blockIdx.x == 0) out[0] = 1.0f;
}

// Pass 1: blur along D (contiguous), compute 5 product channels on the fly.
// Gather form; 11 taps within a 640B row -> L1-hot.
__global__ void pass1(const float* __restrict__ src, const float* __restrict__ ref,
                      float* __restrict__ A, Wts wts) {
    int i = blockIdx.x * blockDim.x + threadIdx.x;
    if (i >= VOL) return;
    int d  = i % DD;
    int hw = i / DD;
    const float* sp = src + (long)hw * DD;
    const float* rp = ref + (long)hw * DD;
    float a0=0.f, a1=0.f, a2=0.f, a3=0.f, a4=0.f;
#pragma unroll
    for (int t = 0; t < KS; ++t) {
        int z = mirror(d + t - PAD, DD);
        float wt = wts.w[t];
        float s = sp[z], r = rp[z];
        a0 += wt*s; a1 += wt*r; a2 += wt*s*s; a3 += wt*r*r; a4 += wt*s*r;
    }
    A[0L*VOL + i] = a0;
    A[1L*VOL + i] = a1;
    A[2L*VOL + i] = a2;
    A[3L*VOL + i] = a3;
    A[4L*VOL + i] = a4;
}

// Pass 2: blur along W. Sliding-window: thread fixes (c,h,d), walks TW outputs
// along w keeping an 11-deep register window. Loads sequential, elements read
// (TW+10)/TW ~= 1.6x instead of 11x.
__global__ void pass2(const float* __restrict__ A, float* __restrict__ Bf, Wts wts) {
    // grid: chunks (WW/TW) x (5*HH*DD / 256)
    const int colsPerChunk = 5 * HH * DD / 256;          // 500 blocks
    int chunk = blockIdx.x / colsPerChunk;
    int blk   = blockIdx.x % colsPerChunk;
    int cidx  = blk * 256 + threadIdx.x;                 // 0 .. 5*HH*DD-1
    int c   = cidx / (HH * DD);
    int rem = cidx % (HH * DD);
    int h   = rem / DD;
    int d   = rem % DD;
    const int w0 = chunk * TW;
    const float* base = A + (long)c * VOL + (long)h * WW * DD + d;
    float*       obase = Bf + (long)c * VOL + (long)h * WW * DD + d;

    float win[KS];
#pragma unroll
    for (int k = 0; k < KS; ++k)
        win[k] = base[(long)mirror(w0 - PAD + k, WW) * DD];

    for (int w = w0; w < w0 + TW; ++w) {
        float acc = 0.f;
#pragma unroll
        for (int k = 0; k < KS; ++k) acc += wts.w[k] * win[k];
        obase[(long)w * DD] = acc;
        // shift + load next (w+6 <= 165 -> mirror valid)
        float nxt = base[(long)mirror(w + PAD + 1, WW) * DD];
#pragma unroll
        for (int k = 0; k < KS - 1; ++k) win[k] = win[k + 1];
        win[KS - 1] = nxt;
    }
}

// Pass 3: blur along H (sliding window, 5 channels), SSIM formula, reduce.
__global__ void pass3(const float* __restrict__ Bf, float* __restrict__ out,
                      Wts wts, float scale) {
    // grid: chunks (HH/TH) x (WW*DD/256)
    const int colsPerChunk = WW * DD / 256;              // 100 blocks
    int chunk = blockIdx.x / colsPerChunk;
    int blk   = blockIdx.x % colsPerChunk;
    int col   = blk * 256 + threadIdx.x;                 // w*DD + d, 0..25599
    const int h0 = chunk * TH;

    const float* base0 = Bf + 0L * VOL + col;
    const float* base1 = Bf + 1L * VOL + col;
    const float* base2 = Bf + 2L * VOL + col;
    const float* base3 = Bf + 3L * VOL + col;
    const float* base4 = Bf + 4L * VOL + col;
    const long HSTRIDE = (long)WW * DD;

    float w0a[KS], w1a[KS], w2a[KS], w3a[KS], w4a[KS];
#pragma unroll
    for (int k = 0; k < KS; ++k) {
        long off = (long)mirror(h0 - PAD + k, HH) * HSTRIDE;
        w0a[k] = base0[off]; w1a[k] = base1[off]; w2a[k] = base2[off];
        w3a[k] = base3[off]; w4a[k] = base4[off];
    }

    float ssum = 0.f;
    for (int h = h0; h < h0 + TH; ++h) {
        float mu1=0.f, mu2=0.f, m11=0.f, m22=0.f, m12=0.f;
#pragma unroll
        for (int k = 0; k < KS; ++k) {
            float wt = wts.w[k];
            mu1 += wt * w0a[k]; mu2 += wt * w1a[k]; m11 += wt * w2a[k];
            m22 += wt * w3a[k]; m12 += wt * w4a[k];
        }
        float mu1sq = mu1*mu1, mu2sq = mu2*mu2, mu12 = mu1*mu2;
        float s1 = m11 - mu1sq, s2 = m22 - mu2sq, s12 = m12 - mu12;
        const float C1 = 1e-4f, C2 = 9e-4f;
        float num = (2.f*mu12 + C1) * (2.f*s12 + C2);
        float den = (mu1sq + mu2sq + C1) * (s1 + s2 + C2);
        ssum += num / (den + 1e-12f);

        long off = (long)mirror(h + PAD + 1, HH) * HSTRIDE;
        float n0 = base0[off], n1 = base1[off], n2 = base2[off],
              n3 = base3[off], n4 = base4[off];
#pragma unroll
        for (int k = 0; k < KS - 1; ++k) {
            w0a[k] = w0a[k+1]; w1a[k] = w1a[k+1]; w2a[k] = w2a[k+1];
            w3a[k] = w3a[k+1]; w4a[k] = w4a[k+1];
        }
        w0a[KS-1] = n0; w1a[KS-1] = n1; w2a[KS-1] = n2;
        w3a[KS-1] = n3; w4a[KS-1] = n4;
    }

    // 64-lane wave reduce, then block reduce, one atomic per block.
#pragma unroll
    for (int off = 32; off > 0; off >>= 1)
        ssum += __shfl_down(ssum, off, 64);
    __shared__ float lsum[4];
    int lane = threadIdx.x & 63, wid = threadIdx.x >> 6;
    if (lane == 0) lsum[wid] = ssum;
    __syncthreads();
    if (threadIdx.x == 0) {
        float s = lsum[0] + lsum[1] + lsum[2] + lsum[3];
        atomicAdd(out, -s * scale);
    }
}

// Fallback: brute-force 11^3 taps per voxel (only if ws too small).
__global__ void brute(const float* __restrict__ src, const float* __restrict__ ref,
                      float* __restrict__ out, Wts wts, float scale) {
    long gi = (long)blockIdx.x * blockDim.x + threadIdx.x;
    float ssim = 0.f;
    if (gi < NTOT) {
        int v = (int)(gi % VOL);
        int b = (int)(gi / VOL);
        int d = v % DD;
        int w = (v / DD) % WW;
        int h = v / (DD*WW);
        const float* sp = src + (long)b * VOL;
        const float* rp = ref + (long)b * VOL;
        float a0=0.f,a1=0.f,a2=0.f,a3=0.f,a4=0.f;
        for (int i = 0; i < KS; ++i) {
            int hm = mirror(h + i - PAD, HH);
            float wx = wts.w[i];
            for (int j = 0; j < KS; ++j) {
                int wm = mirror(w + j - PAD, WW);
                float wxy = wx * wts.w[j];
                const float* sr = sp + ((long)hm*WW + wm) * DD;
                const float* rr = rp + ((long)hm*WW + wm) * DD;
                for (int k = 0; k < KS; ++k) {
                    int dm = mirror(d + k - PAD, DD);
                    float wt = wxy * wts.w[k];
                    float s = sr[dm], r = rr[dm];
                    a0 += wt*s; a1 += wt*r; a2 += wt*s*s; a3 += wt*r*r; a4 += wt*s*r;
                }
            }
        }
        float mu1sq = a0*a0, mu2sq = a1*a1, mu12 = a0*a1;
        float s1 = a2 - mu1sq, s2 = a3 - mu2sq, s12 = a4 - mu12;
        const float C1 = 1e-4f, C2 = 9e-4f;
        float num = (2.f*mu12 + C1) * (2.f*s12 + C2);
        float den = (mu1sq + mu2sq + C1) * (s1 + s2 + C2);
        ssim = num / (den + 1e-12f);
    }
#pragma unroll
    for (int off = 32; off > 0; off >>= 1)
        ssim += __shfl_down(ssim, off, 64);
    __shared__ float lsum[4];
    int lane = threadIdx.x & 63, wid = threadIdx.x >> 6;
    if (lane == 0) lsum[wid] = ssim;
    __syncthreads();
    if (threadIdx.x == 0) {
        float s = lsum[0] + lsum[1] + lsum[2] + lsum[3];
        atomicAdd(out, -s * scale);
    }
}

extern "C" void kernel_launch(void* const* d_in, const int* in_sizes, int n_in,
                              void* d_out, int out_size, void* d_ws, size_t ws_size,
                              hipStream_t stream) {
    const float* src = (const float*)d_in[0];
    const float* ref = (const float*)d_in[1];
    float* out = (float*)d_out;

    Wts wts;
    {
        double g[KS], s = 0.0;
        for (int i = 0; i < KS; ++i) {
            double a = (double)i - (KS - 1) / 2.0;
            g[i] = exp(-(a*a) / (2.0 * 1.5 * 1.5));
            s += g[i];
        }
        for (int i = 0; i < KS; ++i) wts.w[i] = (float)(g[i] / s);
    }

    const float scale = 1.0f / (float)NTOT;
    const size_t bufBytes = (size_t)5 * VOL * sizeof(float);   // 81,920,000
    const size_t need = 2 * bufBytes;                          // 163,840,000

    init_out<<<1, 64, 0, stream>>>(out);

    if (ws_size >= need) {
        float* A  = (float*)d_ws;
        float* Bf = (float*)((char*)d_ws + bufBytes);
        const int BLK = 256;
        const int g1 = (VOL + BLK - 1) / BLK;                  // 16000
        const int g2 = (WW / TW) * (5 * HH * DD / BLK);        // 10 * 500 = 5000
        const int g3 = (HH / TH) * (WW * DD / BLK);            // 10 * 100 = 1000
        for (int b = 0; b < NBATCH; ++b) {
            pass1<<<g1, BLK, 0, stream>>>(src + (long)b*VOL, ref + (long)b*VOL, A, wts);
            pass2<<<g2, BLK, 0, stream>>>(A, Bf, wts);
            pass3<<<g3, BLK, 0, stream>>>(Bf, out, wts, scale);
        }
    } else {
        const int BLK = 256;
        const long g = (NTOT + BLK - 1) / BLK;
        brute<<<(int)g, BLK, 0, stream>>>(src, ref, out, wts, scale);
    }
}

// Round 3
// 213.421 us; speedup vs baseline: 3.4680x; 1.2877x over previous
//
#include <hip/hip_runtime.h>
#include <math.h>

#define HH 160
#define WW 160
#define DD 160
#define VOL (HH*WW*DD)          // 4,096,000
#define KS 11
#define PAD 5
#define NBATCH 2
#define NTOT (NBATCH*VOL)
#define WCH 32                   // w-outputs per thread in k1 (5 chunks)
#define HCH 32                   // h-outputs per thread in k2 (5 chunks)

struct Wts { float w[KS]; };

__device__ __forceinline__ int mirror(int i, int n) {
    if (i < 0) i = -i;
    if (i >= n) i = 2*n - 2 - i;
    return i;
}

__global__ void init_out(float* out) {
    if (threadIdx.x == 0 && blockIdx.x == 0) out[0] = 1.0f;
}

// k1: fused D-blur + W-blur. Thread fixes (b,h,d), walks a 32-wide w chunk.
// Per step: 11 contiguous-d taps of src/ref (mirrored offsets precomputed,
// loop-invariant) -> 5-channel D-blur in regs -> delay-line ring accumulators
// for the W-blur (static ring indices, no shifts). Writes B = W(D(chan)).
__global__ __launch_bounds__(256) void k1(const float* __restrict__ src,
                                          const float* __restrict__ ref,
                                          float* __restrict__ B, Wts wts) {
    // grid: NBATCH * (WW/WCH) * (HH*DD/256) = 2*5*100 = 1000
    const int colsBlocks = HH * DD / 256;            // 100
    int colblk = blockIdx.x % colsBlocks;
    int rest   = blockIdx.x / colsBlocks;
    int wch    = rest % (WW / WCH);
    int b      = rest / (WW / WCH);
    int col    = colblk * 256 + threadIdx.x;         // h*DD + d
    int h = col / DD, d = col % DD;
    const int w0 = wch * WCH;

    const float* sp = src + (size_t)b * VOL + (size_t)h * WW * DD;
    const float* rp = ref + (size_t)b * VOL + (size_t)h * WW * DD;
    float*       op = B   + (size_t)b * 5 * VOL + (size_t)h * WW * DD + d;

    int midx[KS];
#pragma unroll
    for (int k = 0; k < KS; ++k) midx[k] = mirror(d - PAD + k, DD);

    float acc[5][KS];
#pragma unroll
    for (int c = 0; c < 5; ++c)
#pragma unroll
        for (int s = 0; s < KS; ++s) acc[c][s] = 0.f;

    const int NSTEP = WCH + 2 * PAD;                 // 42
    for (int tb = 0; tb < 44; tb += 11) {
#pragma unroll
        for (int ts = 0; ts < 11; ++ts) {
            int t = tb + ts;
            if (t < NSTEP) {
                int wm   = mirror(w0 - PAD + t, WW); // tap w-position (uniform)
                int woff = wm * DD;
                // 5-channel D-blur at (h, wm, d)
                float mu1 = 0.f, mu2 = 0.f, m11 = 0.f, m22 = 0.f, m12 = 0.f;
#pragma unroll
                for (int k = 0; k < KS; ++k) {
                    float s = sp[woff + midx[k]];
                    float r = rp[woff + midx[k]];
                    float wt = wts.w[k];
                    float p = wt * s, q = wt * r;
                    mu1 += p; mu2 += q;
                    m11 = fmaf(p, s, m11);
                    m22 = fmaf(q, r, m22);
                    m12 = fmaf(p, r, m12);
                }
                float v[5] = {mu1, mu2, m11, m22, m12};
                // delay-line: contribute to the 11 pending w-outputs
#pragma unroll
                for (int m = 0; m < 11; ++m) {
                    int slot = (ts + m) % 11;        // static after unroll
                    float wt = wts.w[10 - m];
#pragma unroll
                    for (int c = 0; c < 5; ++c)
                        acc[c][slot] = fmaf(wt, v[c], acc[c][slot]);
                }
                // emit slot ts: output w index o = w0 - 10 + t
                int o = w0 - 10 + t;
                if (t >= 10) {
#pragma unroll
                    for (int c = 0; c < 5; ++c)
                        op[(size_t)c * VOL + (size_t)o * DD] = acc[c][ts];
                }
#pragma unroll
                for (int c = 0; c < 5; ++c) acc[c][ts] = 0.f;
            }
        }
    }
}

// k2: H-blur of the 5 B-channels via the same delay-line, SSIM at emission,
// block reduction, one atomic per block.
__global__ __launch_bounds__(256) void k2(const float* __restrict__ B,
                                          float* __restrict__ out,
                                          Wts wts, float scale) {
    // grid: NBATCH * (HH/HCH) * (WW*DD/256) = 2*5*100 = 1000
    const int colsBlocks = WW * DD / 256;            // 100
    int colblk = blockIdx.x % colsBlocks;
    int rest   = blockIdx.x / colsBlocks;
    int hch    = rest % (HH / HCH);
    int b      = rest / (HH / HCH);
    int col    = colblk * 256 + threadIdx.x;         // w*DD + d
    const int h0 = hch * HCH;
    const float* p = B + (size_t)b * 5 * VOL + col;
    const size_t HS = (size_t)WW * DD;

    float acc[5][KS];
#pragma unroll
    for (int c = 0; c < 5; ++c)
#pragma unroll
        for (int s = 0; s < KS; ++s) acc[c][s] = 0.f;

    float ssum = 0.f;
    const int NSTEP = HCH + 2 * PAD;                 // 42
    for (int tb = 0; tb < 44; tb += 11) {
#pragma unroll
        for (int ts = 0; ts < 11; ++ts) {
            int t = tb + ts;
            if (t < NSTEP) {
                int hm = mirror(h0 - PAD + t, HH);
                size_t off = (size_t)hm * HS;
                float v0 = p[off];
                float v1 = p[off + 1 * (size_t)VOL];
                float v2 = p[off + 2 * (size_t)VOL];
                float v3 = p[off + 3 * (size_t)VOL];
                float v4 = p[off + 4 * (size_t)VOL];
#pragma unroll
                for (int m = 0; m < 11; ++m) {
                    int slot = (ts + m) % 11;
                    float wt = wts.w[10 - m];
                    acc[0][slot] = fmaf(wt, v0, acc[0][slot]);
                    acc[1][slot] = fmaf(wt, v1, acc[1][slot]);
                    acc[2][slot] = fmaf(wt, v2, acc[2][slot]);
                    acc[3][slot] = fmaf(wt, v3, acc[3][slot]);
                    acc[4][slot] = fmaf(wt, v4, acc[4][slot]);
                }
                if (t >= 10) {
                    float mu1 = acc[0][ts], mu2 = acc[1][ts];
                    float m11 = acc[2][ts], m22 = acc[3][ts], m12 = acc[4][ts];
                    float mu1sq = mu1 * mu1, mu2sq = mu2 * mu2, mu12 = mu1 * mu2;
                    float s1 = m11 - mu1sq, s2 = m22 - mu2sq, s12 = m12 - mu12;
                    const float C1 = 1e-4f, C2 = 9e-4f;
                    float num = (2.f * mu12 + C1) * (2.f * s12 + C2);
                    float den = (mu1sq + mu2sq + C1) * (s1 + s2 + C2);
                    ssum += num / (den + 1e-12f);
                }
#pragma unroll
                for (int c = 0; c < 5; ++c) acc[c][ts] = 0.f;
            }
        }
    }

#pragma unroll
    for (int off = 32; off > 0; off >>= 1)
        ssum += __shfl_down(ssum, off, 64);
    __shared__ float lsum[4];
    int lane = threadIdx.x & 63, wid = threadIdx.x >> 6;
    if (lane == 0) lsum[wid] = ssum;
    __syncthreads();
    if (threadIdx.x == 0) {
        float s = lsum[0] + lsum[1] + lsum[2] + lsum[3];
        atomicAdd(out, -s * scale);
    }
}

// Fallback: brute-force 11^3 taps per voxel (only if ws too small).
__global__ void brute(const float* __restrict__ src, const float* __restrict__ ref,
                      float* __restrict__ out, Wts wts, float scale) {
    long gi = (long)blockIdx.x * blockDim.x + threadIdx.x;
    float ssim = 0.f;
    if (gi < NTOT) {
        int v = (int)(gi % VOL);
        int b = (int)(gi / VOL);
        int d = v % DD;
        int w = (v / DD) % WW;
        int h = v / (DD * WW);
        const float* sp = src + (long)b * VOL;
        const float* rp = ref + (long)b * VOL;
        float a0 = 0.f, a1 = 0.f, a2 = 0.f, a3 = 0.f, a4 = 0.f;
        for (int i = 0; i < KS; ++i) {
            int hm = mirror(h + i - PAD, HH);
            float wx = wts.w[i];
            for (int j = 0; j < KS; ++j) {
                int wm = mirror(w + j - PAD, WW);
                float wxy = wx * wts.w[j];
                const float* sr = sp + ((long)hm * WW + wm) * DD;
                const float* rr = rp + ((long)hm * WW + wm) * DD;
                for (int k = 0; k < KS; ++k) {
                    int dm = mirror(d + k - PAD, DD);
                    float wt = wxy * wts.w[k];
                    float s = sr[dm], r = rr[dm];
                    a0 += wt * s; a1 += wt * r; a2 += wt * s * s;
                    a3 += wt * r * r; a4 += wt * s * r;
                }
            }
        }
        float mu1sq = a0 * a0, mu2sq = a1 * a1, mu12 = a0 * a1;
        float s1 = a2 - mu1sq, s2 = a3 - mu2sq, s12 = a4 - mu12;
        const float C1 = 1e-4f, C2 = 9e-4f;
        float num = (2.f * mu12 + C1) * (2.f * s12 + C2);
        float den = (mu1sq + mu2sq + C1) * (s1 + s2 + C2);
        ssim = num / (den + 1e-12f);
    }
#pragma unroll
    for (int off = 32; off > 0; off >>= 1)
        ssim += __shfl_down(ssim, off, 64);
    __shared__ float lsum[4];
    int lane = threadIdx.x & 63, wid = threadIdx.x >> 6;
    if (lane == 0) lsum[wid] = ssim;
    __syncthreads();
    if (threadIdx.x == 0) {
        float s = lsum[0] + lsum[1] + lsum[2] + lsum[3];
        atomicAdd(out, -s * scale);
    }
}

extern "C" void kernel_launch(void* const* d_in, const int* in_sizes, int n_in,
                              void* d_out, int out_size, void* d_ws, size_t ws_size,
                              hipStream_t stream) {
    const float* src = (const float*)d_in[0];
    const float* ref = (const float*)d_in[1];
    float* out = (float*)d_out;

    Wts wts;
    {
        double g[KS], s = 0.0;
        for (int i = 0; i < KS; ++i) {
            double a = (double)i - (KS - 1) / 2.0;
            g[i] = exp(-(a * a) / (2.0 * 1.5 * 1.5));
            s += g[i];
        }
        for (int i = 0; i < KS; ++i) wts.w[i] = (float)(g[i] / s);
    }

    const float scale = 1.0f / (float)NTOT;
    const size_t need = (size_t)NBATCH * 5 * VOL * sizeof(float);  // 163.84 MB

    init_out<<<1, 64, 0, stream>>>(out);

    if (ws_size >= need) {
        float* B = (float*)d_ws;
        const int g1 = NBATCH * (WW / WCH) * (HH * DD / 256);  // 1000
        const int g2 = NBATCH * (HH / HCH) * (WW * DD / 256);  // 1000
        k1<<<g1, 256, 0, stream>>>(src, ref, B, wts);
        k2<<<g2, 256, 0, stream>>>(B, out, wts, scale);
    } else {
        const int BLK = 256;
        const long g = (NTOT + BLK - 1) / BLK;
        brute<<<(int)g, BLK, 0, stream>>>(src, ref, out, wts, scale);
    }
}